// Round 1
// 257.040 us; speedup vs baseline: 1.0320x; 1.0320x over previous
//
#include <hip/hip_runtime.h>
#include <hip/hip_bf16.h>
#include <cstdint>
#include <cstddef>

typedef __bf16 bf16_t;
typedef __bf16 bf16x8 __attribute__((ext_vector_type(8)));
typedef __bf16 bf16x4 __attribute__((ext_vector_type(4)));
typedef float  f32x4  __attribute__((ext_vector_type(4)));

#define KDIM 1024
#define NT   16        // KDIM / 64 K-tiles

// ---------------------------------------------------------------------------
// Kernel 1: per-row softmax(mod) + 1, multiply by x, emit bf16.
// ---------------------------------------------------------------------------
__global__ void att_scale_kernel(const float* __restrict__ x,
                                 const float* __restrict__ mod,
                                 bf16_t* __restrict__ a, int D) {
  const int b = blockIdx.x;
  const int t = threadIdx.x;
  const size_t row = (size_t)b * D;

  float4 mv = ((const float4*)(mod + row))[t];
  float mx = fmaxf(fmaxf(mv.x, mv.y), fmaxf(mv.z, mv.w));
#pragma unroll
  for (int o = 32; o > 0; o >>= 1) mx = fmaxf(mx, __shfl_xor(mx, o));

  __shared__ float redmax[4];
  __shared__ float redsum[4];
  const int wave = t >> 6, lane = t & 63;
  if (lane == 0) redmax[wave] = mx;
  __syncthreads();
  mx = fmaxf(fmaxf(redmax[0], redmax[1]), fmaxf(redmax[2], redmax[3]));

  float4 e;
  e.x = __expf(mv.x - mx); e.y = __expf(mv.y - mx);
  e.z = __expf(mv.z - mx); e.w = __expf(mv.w - mx);
  float s = (e.x + e.y) + (e.z + e.w);
#pragma unroll
  for (int o = 32; o > 0; o >>= 1) s += __shfl_xor(s, o);
  if (lane == 0) redsum[wave] = s;
  __syncthreads();
  s = (redsum[0] + redsum[1]) + (redsum[2] + redsum[3]);

  const float inv = 1.0f / s;
  float4 xv = ((const float4*)(x + row))[t];
  bf16x4 o4;
  o4[0] = (bf16_t)((e.x * inv + 1.0f) * xv.x);
  o4[1] = (bf16_t)((e.y * inv + 1.0f) * xv.y);
  o4[2] = (bf16_t)((e.z * inv + 1.0f) * xv.z);
  o4[3] = (bf16_t)((e.w * inv + 1.0f) * xv.w);
  *((bf16x4*)(a + row) + t) = o4;
}

// ---------------------------------------------------------------------------
// Kernel 2: fp32 -> bf16 cast of W.
// ---------------------------------------------------------------------------
__global__ void cast_w_kernel(const float* __restrict__ W,
                              bf16_t* __restrict__ Wb) {
  const size_t i = ((size_t)blockIdx.x * blockDim.x + threadIdx.x) * 8;
  float4 u = *(const float4*)(W + i);
  float4 v = *(const float4*)(W + i + 4);
  bf16x8 o;
  o[0] = (bf16_t)u.x; o[1] = (bf16_t)u.y; o[2] = (bf16_t)u.z; o[3] = (bf16_t)u.w;
  o[4] = (bf16_t)v.x; o[5] = (bf16_t)v.y; o[6] = (bf16_t)v.z; o[7] = (bf16_t)v.w;
  *(bf16x8*)(Wb + i) = o;
}

// ---------------------------------------------------------------------------
// Kernel 3: 256x256-tile 8-phase bf16 GEMM (B^T input), counted vmcnt.
//   C[m][n] = sum_k A[m][k] * B[n][k];  A:(M,K) bf16, B:(N,K) bf16, C fp32.
// 8 waves (2M x 4N); per-wave output 128x64; BK=64; LDS = 2 buf x (A 32K + B 32K).
// XOR swizzle (c8 ^= row&7) applied on global source at stage time (LDS dest
// stays linear for global_load_lds) and on the column index at ds_read time.
// Schedule per K-tile u (4 phases == 4 row-quadrants of the wave's 128 rows):
//   ph0: read B-frags(all)+A-frags(q0); issue A-half0(u+1)   [buf(u+1) A free since group u-1]
//   ph1: read A(q1);                    issue A-half1(u+1)
//   ph2: read A(q2);                    issue B-half0(u+2)   [buf(u) B fully read in ph0]
//   ph3: read A(q3);                    issue B-half1(u+2); vmcnt(4) -> only B(u+2) in flight
// Each phase: {reads ∥ issue} -> s_barrier -> lgkmcnt(0) -> setprio(1) 16 MFMA -> s_barrier.
// ---------------------------------------------------------------------------
__global__ __launch_bounds__(512, 2) void gemm256_kernel(
    const bf16_t* __restrict__ A, const bf16_t* __restrict__ B,
    float* __restrict__ C, int M, int N) {
  __shared__ __align__(16) bf16_t lds[2 * 32768];   // 128 KiB

  const int tid  = threadIdx.x;
  const int wave = tid >> 6;
  const int lane = tid & 63;
  const int quad = lane >> 4;
  const int l16  = lane & 15;
  const int wm   = wave >> 2;      // 0..1 -> 128 M-rows
  const int wn   = wave & 3;       // 0..3 -> 64 N-cols

  // XCD-aware bijective swizzle (nwg = 512, % 8 == 0)
  const int nwg = gridDim.x;
  int flat = blockIdx.x;
  flat = (flat & 7) * (nwg >> 3) + (flat >> 3);
  const int ntiles = N >> 8;
  const int m0 = (flat / ntiles) << 8;
  const int n0 = (flat % ntiles) << 8;

  // Staging: slot s = i*512 + tid within a half-tile (128 rows x 8 c8-groups).
  // row_local = s>>3 (+64 per instr i, +128 per half h: both ≡ 0 mod 8),
  // LDS c8 = s&7 = tid&7, global c8 = (tid&7) ^ (row&7).
  const int trow = tid >> 3;                       // 0..63
  const int colg = (tid & 7) ^ (trow & 7);
  const bf16_t* aSrc = A + (size_t)(m0 + trow) * KDIM + colg * 8;
  const bf16_t* bSrc = B + (size_t)(n0 + trow) * KDIM + colg * 8;
  const int ldsW = wave * 512;                     // wave-uniform dest offset (elems)

#define GLDS(src_, dst_) __builtin_amdgcn_global_load_lds( \
      (const __attribute__((address_space(1))) void*)(src_), \
      (__attribute__((address_space(3))) void*)(dst_), 16, 0, 0)

#define ISSUE_A(h, u_) do { \
      const bf16_t* s_ = aSrc + (size_t)((h) * 128) * KDIM + (u_) * 64; \
      bf16_t* d_ = lds + ((u_) & 1) * 32768 + (h) * 8192 + ldsW; \
      GLDS(s_, d_); \
      GLDS(s_ + (size_t)64 * KDIM, d_ + 4096); \
    } while (0)

#define ISSUE_B(h, u_) do { \
      const bf16_t* s_ = bSrc + (size_t)((h) * 128) * KDIM + (u_) * 64; \
      bf16_t* d_ = lds + ((u_) & 1) * 32768 + 16384 + (h) * 8192 + ldsW; \
      GLDS(s_, d_); \
      GLDS(s_ + (size_t)64 * KDIM, d_ + 4096); \
    } while (0)

  // Prologue: tile0 A+B (4 HT), tile1 B (2 HT) = 12 loads/wave.
  ISSUE_A(0, 0); ISSUE_A(1, 0);
  ISSUE_B(0, 0); ISSUE_B(1, 0);
  ISSUE_B(0, 1); ISSUE_B(1, 1);

  f32x4 acc[8][4];
#pragma unroll
  for (int i = 0; i < 8; ++i)
#pragma unroll
    for (int j = 0; j < 4; ++j) acc[i][j] = (f32x4){0.f, 0.f, 0.f, 0.f};

  const int aBase = (wm * 128 + l16) * 64;
  const int bBase = (wn * 64 + l16) * 64;
  const int c0 = ((quad)     ^ (l16 & 7)) * 8;     // kt=0 swizzled column (elems)
  const int c1 = ((4 + quad) ^ (l16 & 7)) * 8;     // kt=1

  // Wait for tile0 (first 8 loads); tile1's B (last 4) stays in flight.
  asm volatile("s_waitcnt vmcnt(4)" ::: "memory");
  __builtin_amdgcn_s_barrier();

  bf16x8 bfr[4][2];

#define PHASE(q_, ISSUE_STMT, WAIT_STMT) do { \
      bf16x8 af[2][2]; \
      _Pragma("unroll") \
      for (int i = 0; i < 2; ++i) { \
        af[i][0] = *(const bf16x8*)(At + aBase + ((q_) * 32 + i * 16) * 64 + c0); \
        af[i][1] = *(const bf16x8*)(At + aBase + ((q_) * 32 + i * 16) * 64 + c1); \
      } \
      ISSUE_STMT; \
      asm volatile("" ::: "memory"); \
      __builtin_amdgcn_s_barrier(); \
      asm volatile("s_waitcnt lgkmcnt(0)" ::: "memory"); \
      __builtin_amdgcn_s_setprio(1); \
      _Pragma("unroll") \
      for (int i = 0; i < 2; ++i) \
        _Pragma("unroll") \
        for (int j = 0; j < 4; ++j) { \
          acc[(q_) * 2 + i][j] = __builtin_amdgcn_mfma_f32_16x16x32_bf16( \
              af[i][0], bfr[j][0], acc[(q_) * 2 + i][j], 0, 0, 0); \
          acc[(q_) * 2 + i][j] = __builtin_amdgcn_mfma_f32_16x16x32_bf16( \
              af[i][1], bfr[j][1], acc[(q_) * 2 + i][j], 0, 0, 0); \
        } \
      __builtin_amdgcn_s_setprio(0); \
      WAIT_STMT; \
      asm volatile("" ::: "memory"); \
      __builtin_amdgcn_s_barrier(); \
    } while (0)

#pragma unroll 1
  for (int u = 0; u < NT; ++u) {
    const bf16_t* At = lds + (u & 1) * 32768;
    const bf16_t* Bt = At + 16384;

    // Phase 0 extra: load the wave's full B panel for this K-tile (8 reads).
#pragma unroll
    for (int j = 0; j < 4; ++j) {
      bfr[j][0] = *(const bf16x8*)(Bt + bBase + j * 16 * 64 + c0);
      bfr[j][1] = *(const bf16x8*)(Bt + bBase + j * 16 * 64 + c1);
    }
    PHASE(0, if (u + 1 < NT) ISSUE_A(0, u + 1), (void)0);
    PHASE(1, if (u + 1 < NT) ISSUE_A(1, u + 1), (void)0);
    PHASE(2, if (u + 2 < NT) ISSUE_B(0, u + 2), (void)0);
    PHASE(3, if (u + 2 < NT) ISSUE_B(1, u + 2),
          if (u < NT - 2) { asm volatile("s_waitcnt vmcnt(4)" ::: "memory"); }
          else            { asm volatile("s_waitcnt vmcnt(0)" ::: "memory"); });
  }

  // Epilogue: C/D 16x16 layout: col = l16, row = quad*4 + reg.
#pragma unroll
  for (int ri = 0; ri < 8; ++ri) {
    const int mg = m0 + wm * 128 + ri * 16 + quad * 4;
#pragma unroll
    for (int j = 0; j < 4; ++j) {
      const int ng = n0 + wn * 64 + j * 16 + l16;
#pragma unroll
      for (int r = 0; r < 4; ++r)
        C[(size_t)(mg + r) * N + ng] = acc[ri][j][r];
    }
  }
}

// ---------------------------------------------------------------------------
extern "C" void kernel_launch(void* const* d_in, const int* in_sizes, int n_in,
                              void* d_out, int out_size, void* d_ws, size_t ws_size,
                              hipStream_t stream) {
  const float* x   = (const float*)d_in[0];
  const float* mod = (const float*)d_in[1];
  const float* W   = (const float*)d_in[2];
  float* out = (float*)d_out;

  const int D = 1024;
  const int Bn = in_sizes[0] / D;  // 8192
  const int Cn = in_sizes[2] / D;  // 4096

  bf16_t* a  = (bf16_t*)d_ws;                                             // B*D bf16
  bf16_t* Wb = (bf16_t*)((char*)d_ws + (size_t)Bn * D * sizeof(bf16_t));  // C*D bf16

  att_scale_kernel<<<Bn, 256, 0, stream>>>(x, mod, a, D);
  cast_w_kernel<<<((size_t)Cn * D) / (256 * 8), 256, 0, stream>>>(W, Wb);

  const int nwg = (Bn / 256) * (Cn / 256);  // 32*16 = 512, % 8 == 0
  gemm256_kernel<<<nwg, 512, 0, stream>>>(a, Wb, out, Bn, Cn);
}